// Round 7
// baseline (378.575 us; speedup 1.0000x reference)
//
#include <hip/hip_runtime.h>
#include <hip/hip_bf16.h>

// Problem constants (fixed by reference setup_inputs)
constexpr int Bn = 128;   // batch
constexpr int Tn = 32;    // timesteps
constexpr int Dn = 6400;  // input dim (K)
constexpr int Hn = 1000;  // hidden  (N)
constexpr int An = 4;     // actions
constexpr int Mn = Bn * Tn;   // 4096 GEMM rows
constexpr int Npad = 1024;    // W rows padded -> no N-guards in GEMM

constexpr int KS = Dn / 32;   // 200 k-chunks of 32
constexpr int MC = Mn / 16;   // 256 m-chunks of 16 rows
constexpr int NC = Npad / 16; // 64  n-chunks of 16 rows

typedef _Float16 half8 __attribute__((ext_vector_type(8)));
typedef _Float16 half4 __attribute__((ext_vector_type(4)));
typedef float floatx4 __attribute__((ext_vector_type(4)));

// Workspace layouts (bytes)
constexpr size_t H1_BYTES  = (size_t)Mn * Hn * 4;       // 16,384,000
constexpr size_t XS_BYTES  = (size_t)Mn * Dn * 2;       // per split
constexpr size_t WSp_BYTES = (size_t)Npad * Dn * 2;     // per split
constexpr size_t WS_R7     = H1_BYTES + 2 * XS_BYTES + 2 * WSp_BYTES;      // 147,456,000
constexpr size_t WS_SPLITK = 2 * H1_BYTES + 2 * XS_BYTES + 2 * WSp_BYTES;  // 163,840,000
constexpr size_t WS_SK3    = 3 * H1_BYTES + 2 * XS_BYTES + 2 * WSp_BYTES;  // 180,224,000

__device__ __forceinline__ void async16(const void* g, void* l) {
    __builtin_amdgcn_global_load_lds(
        (const __attribute__((address_space(1))) void*)g,
        (__attribute__((address_space(3))) void*)l, 16, 0, 0);
}

// ---------------------------------------------------------------------------
// Pre-pass: fp16 hi/lo split into fragment-chunk layout, both sides 1KB
// coalesced via LDS transpose.
// r12 encoding (verified absmax=0): values pre-scaled by 16 (exact exponent
// shift), lo stored UNSCALED: hi = fp16(16*v), lo = fp16(16*v - hi).  All
// three MFMA products (hi*hi, hi*lo, lo*hi) carry coefficient 1 -> single
// accumulator in the GEMM; epilogue multiplies by 1/256.
// ---------------------------------------------------------------------------
__global__ __launch_bounds__(256)
void cvt2(const float* __restrict__ X, const float* __restrict__ W1,
          _Float16* __restrict__ Xh, _Float16* __restrict__ Xl,
          _Float16* __restrict__ Wh, _Float16* __restrict__ Wl)
{
    constexpr int LD2 = 264;
    __shared__ __align__(16) _Float16 hiS[16][LD2];
    __shared__ __align__(16) _Float16 loS[16][LD2];

    const int tid = threadIdx.x;
    const int lane = tid & 63;
    const int w = tid >> 6;
    const int bx = blockIdx.x;

    const float* src;
    _Float16 *dh, *dl;
    int c4, ks0, crow, nrows;
    if (bx < 256 * 25) {                       // X part
        c4 = bx & 255; ks0 = (bx >> 8) * 8;
        src = X; dh = Xh; dl = Xl; crow = MC; nrows = 16;
    } else {                                   // W part (rows >= Hn zeroed)
        const int b2 = bx - 256 * 25;
        c4 = b2 & 63; ks0 = (b2 >> 6) * 8;
        src = W1; dh = Wh; dl = Wl; crow = NC; nrows = Hn - c4 * 16;
    }

#pragma unroll
    for (int j = 0; j < 4; ++j) {
        const int row = w * 4 + j;
        float4 v = make_float4(0.f, 0.f, 0.f, 0.f);
        if (row < nrows)
            v = *(const float4*)(src + (size_t)(c4 * 16 + row) * Dn + ks0 * 32 + lane * 4);
        half4 hi, lo;
        const float vx = v.x * 16.0f, vy = v.y * 16.0f,
                    vz = v.z * 16.0f, vw = v.w * 16.0f;
        hi[0] = (_Float16)vx; lo[0] = (_Float16)(vx - (float)hi[0]);
        hi[1] = (_Float16)vy; lo[1] = (_Float16)(vy - (float)hi[1]);
        hi[2] = (_Float16)vz; lo[2] = (_Float16)(vz - (float)hi[2]);
        hi[3] = (_Float16)vw; lo[3] = (_Float16)(vw - (float)hi[3]);
        *(half4*)&hiS[row][lane * 4] = hi;
        *(half4*)&loS[row][lane * 4] = lo;
    }
    __syncthreads();

    const int lr = lane & 15, lg = lane >> 4;
#pragma unroll
    for (int q = 0; q < 2; ++q) {
        const int ks = w * 2 + q;
        const size_t cbase = ((size_t)(ks0 + ks) * crow + c4) * 512;
        const half8 h = *(const half8*)&hiS[lr][ks * 32 + lg * 8];
        const half8 l = *(const half8*)&loS[lr][ks * 32 + lg * 8];
        *(half8*)(dh + cbase + lane * 8) = h;
        *(half8*)(dl + cbase + lane * 8) = l;
    }
}

// ---------------------------------------------------------------------------
// GEMM primary (r15): 128x128 tile, SPLIT-K=3 -> 768 blocks = 3 blocks/CU.
//
// Post-mortem chain: five structurally different schedules (r8/r9/r11/r12/
// r14) ALL pinned at MfmaUtil 50-54%.  The invariant was occupancy: grid =
// 512 blocks on 256 CUs = 2 blocks/CU hard cap.  The 2 waves/SIMD belong to
// barrier-locked sibling blocks that share the MFMA pipe: their bursts
// serialize, so they finish together and stall together on each body's
// serial head -- no third independent stream to cover it.  (m97-structure
// gets its 874 TF from ~3 independent blocks/CU.)
//
// Fix: split-K=3 -> 768 blocks, 3/CU.  3 independent blocks per CU at
// drifting phases cover each other's stalls.  LDS shrinks to a 3-buffer
// rotation (48 KB -> 3x48=144 <= 160 KB).  The r11 counted-vmcnt audit is
// unchanged: body(it) = [vmcnt(4); s_barrier] -> B(it)->regs -> DMA(it+2)
// -> ds_read buf(it%3) -> 48 MFMA.  At barrier(it) the only outstanding
// vmem is DMA(it+1) (4 ops) -- B(it-1) was register-waited by MFMA(it-1) --
// so vmcnt(4) proves DMA(it) landed; never drains to 0.  DMA(it+2)
// overwrites buf((it+2)%3) whose readers finished before barrier(it).
// NIT = 67/67/66 per kh; triple-unrolled loop keeps buffer indices
// compile-time, one tail body for NIT=67.  T5 setprio wraps the MFMA
// passes (cross-block phase diversity now exists -- m191 regime).
// Regs: acc 64 AGPR + B 32 + A 32 + addr -> ~130 VGPR, no spill.
// ---------------------------------------------------------------------------
__global__ __launch_bounds__(256, 3)
void gemm_sk3(const _Float16* __restrict__ Xh, const _Float16* __restrict__ Xl,
              const _Float16* __restrict__ Wh, const _Float16* __restrict__ Wl,
              float* __restrict__ H1)
{
    __shared__ __align__(16) _Float16 S[3][16][512];   // 48 KB

    const int tid = threadIdx.x;
    const int lane = tid & 63;
    const int w = tid >> 6;
    const int bid = blockIdx.x;            // ((mb*8)+nb)*3 + kh
    const int kh = bid % 3;
    const int nbmb = bid / 3;
    const int nb = nbmb & 7;
    const int mb = nbmb >> 3;
    const int bm8 = mb * 8;
    const int bn8 = nb * 8;
    const int wm = w & 1;
    const int wn = w >> 1;
    const int ks0 = kh * 67;               // 0, 67, 134
    const int NIT = (kh == 2) ? 66 : 67;   // 67+67+66 = 200

    // A staging: wave w stages hi+lo of m-chunks 2w, 2w+1 (4 async16/wave).
    auto issueA = [&](int ks, int buf) {
        _Float16* base = &S[buf][0][0];
#pragma unroll
        for (int r = 0; r < 2; ++r) {
            const int i = w * 2 + r;
            const size_t ga = ((size_t)(ks * MC + bm8 + i)) * 512 + lane * 8;
            async16(Xh + ga, base + (0 + i) * 512);
            async16(Xl + ga, base + (8 + i) * 512);
        }
    };

    // B fragments: direct global->VGPR, lane-contiguous 1 KB per instruction.
    const _Float16* bhp = Wh + ((size_t)(ks0 * NC + bn8 + wn * 4)) * 512 + lane * 8;
    const _Float16* blp = Wl + ((size_t)(ks0 * NC + bn8 + wn * 4)) * 512 + lane * 8;
    constexpr size_t BSTEP = (size_t)NC * 512;         // per-ks advance (halves)

    floatx4 acc[4][4] = {};                            // single accumulator set

    // prologue: DMA(0)->buf0, DMA(1)->buf1 (8 vmem ops outstanding)
    issueA(ks0 + 0, 0);
    issueA(ks0 + 1, 1);

    // Body(IT, BUF): [vmcnt(4); s_barrier] -> B(IT) (8, FIRST) ->
    //                DMA(IT+2)->buf BUFN (4, AFTER B) -> ds_read+MFMA.
#define SK3_BODY(IT, BUF, BUFN)                                                 \
    {                                                                           \
        asm volatile("s_waitcnt vmcnt(4)" ::: "memory");                        \
        __builtin_amdgcn_sched_barrier(0);                                      \
        __builtin_amdgcn_s_barrier();                                           \
        __builtin_amdgcn_sched_barrier(0);                                      \
        half8 bh[4], bl[4];                                                     \
        {                                                                       \
            const size_t bo = (size_t)(IT) * BSTEP;                             \
            _Pragma("unroll")                                                   \
            for (int nt = 0; nt < 4; ++nt) {                                    \
                bh[nt] = *(const half8*)(bhp + bo + nt * 512);                  \
                bl[nt] = *(const half8*)(blp + bo + nt * 512);                  \
            }                                                                   \
        }                                                                       \
        __builtin_amdgcn_sched_barrier(0);                                      \
        if ((IT) + 2 < NIT) issueA(ks0 + (IT) + 2, BUFN);                       \
        __builtin_amdgcn_sched_barrier(0);                                      \
        half8 ah[4], al[4];                                                     \
        _Pragma("unroll")                                                       \
        for (int mt = 0; mt < 4; ++mt) {                                        \
            ah[mt] = *(const half8*)&S[BUF][wm * 4 + mt][lane * 8];             \
            al[mt] = *(const half8*)&S[BUF][8 + wm * 4 + mt][lane * 8];         \
        }                                                                       \
        __builtin_amdgcn_s_setprio(1);                                          \
        _Pragma("unroll")                                                       \
        for (int mt = 0; mt < 4; ++mt)                                          \
            _Pragma("unroll")                                                   \
            for (int nt = 0; nt < 4; ++nt)                                      \
                acc[mt][nt] = __builtin_amdgcn_mfma_f32_16x16x32_f16(ah[mt], bh[nt], acc[mt][nt], 0, 0, 0); \
        _Pragma("unroll")                                                       \
        for (int mt = 0; mt < 4; ++mt)                                          \
            _Pragma("unroll")                                                   \
            for (int nt = 0; nt < 4; ++nt)                                      \
                acc[mt][nt] = __builtin_amdgcn_mfma_f32_16x16x32_f16(ah[mt], bl[nt], acc[mt][nt], 0, 0, 0); \
        _Pragma("unroll")                                                       \
        for (int mt = 0; mt < 4; ++mt)                                          \
            _Pragma("unroll")                                                   \
            for (int nt = 0; nt < 4; ++nt)                                      \
                acc[mt][nt] = __builtin_amdgcn_mfma_f32_16x16x32_f16(al[mt], bh[nt], acc[mt][nt], 0, 0, 0); \
        __builtin_amdgcn_s_setprio(0);                                          \
    }

    // it stays ≡ 0 (mod 3) at loop head -> compile-time buffer indices.
    int it = 0;
    for (; it + 3 <= NIT; it += 3) {
        SK3_BODY(it + 0, 0, 2);
        SK3_BODY(it + 1, 1, 0);
        SK3_BODY(it + 2, 2, 1);
    }
    if (it < NIT) {                        // NIT=67 tail: it=66, buf 0
        SK3_BODY(it, 0, 2);
    }
#undef SK3_BODY

    // epilogue (no bias -- scan adds b1): C/D col=lane&15, row=(lane>>4)*4+r
    // x16 pre-scale on both operands -> result carries 256x; undo here.
    float* H1o = H1 + (size_t)kh * ((size_t)Mn * Hn);
    const int fr = lane & 15;
    const int fq = lane >> 4;
#pragma unroll
    for (int nt = 0; nt < 4; ++nt) {
        const int n = nb * 128 + wn * 64 + nt * 16 + fr;
        if (n >= Hn) continue;
#pragma unroll
        for (int mt = 0; mt < 4; ++mt) {
            const int m = mb * 128 + wm * 64 + mt * 16 + fq * 4;
#pragma unroll
            for (int r = 0; r < 4; ++r)
                H1o[(size_t)(m + r) * Hn + n] = acc[mt][nt][r] * (1.0f / 256.0f);
        }
    }
}

// ---------------------------------------------------------------------------
// GEMM split-K=2 (r14-verified, 140 us): fallback when ws in [163.8, 180.2) MB.
// ---------------------------------------------------------------------------
__global__ __launch_bounds__(256, 2)
void gemm_sk2(const _Float16* __restrict__ Xh, const _Float16* __restrict__ Xl,
              const _Float16* __restrict__ Wh, const _Float16* __restrict__ Wl,
              float* __restrict__ H1)
{
    __shared__ __align__(16) _Float16 S[4][16][512];   // 64 KB

    const int tid = threadIdx.x;
    const int lane = tid & 63;
    const int w = tid >> 6;
    const int kh = blockIdx.x & 1;
    const int nb = (blockIdx.x >> 1) & 7;
    const int mb = blockIdx.x >> 4;
    const int bm8 = mb * 8;
    const int bn8 = nb * 8;
    const int wm = w & 1;
    const int wn = w >> 1;
    const int ks0 = kh * (KS / 2);
    constexpr int NIT = KS / 2;                // 100 (even)

    auto issueA = [&](int ks, int buf) {
        _Float16* base = &S[buf][0][0];
#pragma unroll
        for (int r = 0; r < 2; ++r) {
            const int i = w * 2 + r;
            const size_t ga = ((size_t)(ks * MC + bm8 + i)) * 512 + lane * 8;
            async16(Xh + ga, base + (0 + i) * 512);
            async16(Xl + ga, base + (8 + i) * 512);
        }
    };

    const _Float16* bhp = Wh + ((size_t)(ks0 * NC + bn8 + wn * 4)) * 512 + lane * 8;
    const _Float16* blp = Wl + ((size_t)(ks0 * NC + bn8 + wn * 4)) * 512 + lane * 8;
    constexpr size_t BSTEP = (size_t)NC * 512;

    floatx4 acc[4][4] = {};

    issueA(ks0 + 0, 0);
    issueA(ks0 + 1, 1);

#define SK2_BODY(IT, BUF)                                                       \
    {                                                                           \
        asm volatile("s_waitcnt vmcnt(4)" ::: "memory");                        \
        __builtin_amdgcn_sched_barrier(0);                                      \
        __builtin_amdgcn_s_barrier();                                           \
        __builtin_amdgcn_sched_barrier(0);                                      \
        half8 bh[4], bl[4];                                                     \
        {                                                                       \
            const size_t bo = (size_t)(IT) * BSTEP;                             \
            _Pragma("unroll")                                                   \
            for (int nt = 0; nt < 4; ++nt) {                                    \
                bh[nt] = *(const half8*)(bhp + bo + nt * 512);                  \
                bl[nt] = *(const half8*)(blp + bo + nt * 512);                  \
            }                                                                   \
        }                                                                       \
        __builtin_amdgcn_sched_barrier(0);                                      \
        if ((IT) + 2 < NIT) issueA(ks0 + (IT) + 2, ((IT) + 2) & 3);             \
        __builtin_amdgcn_sched_barrier(0);                                      \
        half8 ah[4], al[4];                                                     \
        _Pragma("unroll")                                                       \
        for (int mt = 0; mt < 4; ++mt) {                                        \
            ah[mt] = *(const half8*)&S[BUF][wm * 4 + mt][lane * 8];             \
            al[mt] = *(const half8*)&S[BUF][8 + wm * 4 + mt][lane * 8];         \
        }                                                                       \
        _Pragma("unroll")                                                       \
        for (int mt = 0; mt < 4; ++mt)                                          \
            _Pragma("unroll")                                                   \
            for (int nt = 0; nt < 4; ++nt)                                      \
                acc[mt][nt] = __builtin_amdgcn_mfma_f32_16x16x32_f16(ah[mt], bh[nt], acc[mt][nt], 0, 0, 0); \
        _Pragma("unroll")                                                       \
        for (int mt = 0; mt < 4; ++mt)                                          \
            _Pragma("unroll")                                                   \
            for (int nt = 0; nt < 4; ++nt)                                      \
                acc[mt][nt] = __builtin_amdgcn_mfma_f32_16x16x32_f16(ah[mt], bl[nt], acc[mt][nt], 0, 0, 0); \
        _Pragma("unroll")                                                       \
        for (int mt = 0; mt < 4; ++mt)                                          \
            _Pragma("unroll")                                                   \
            for (int nt = 0; nt < 4; ++nt)                                      \
                acc[mt][nt] = __builtin_amdgcn_mfma_f32_16x16x32_f16(al[mt], bh[nt], acc[mt][nt], 0, 0, 0); \
    }

    for (int it = 0; it < NIT; it += 4) {
        SK2_BODY(it + 0, 0);
        SK2_BODY(it + 1, 1);
        SK2_BODY(it + 2, 2);
        SK2_BODY(it + 3, 3);
    }
#undef SK2_BODY

    float* H1o = H1 + (size_t)kh * ((size_t)Mn * Hn);
    const int fr = lane & 15;
    const int fq = lane >> 4;
#pragma unroll
    for (int nt = 0; nt < 4; ++nt) {
        const int n = nb * 128 + wn * 64 + nt * 16 + fr;
        if (n >= Hn) continue;
#pragma unroll
        for (int mt = 0; mt < 4; ++mt) {
            const int m = mb * 128 + wm * 64 + mt * 16 + fq * 4;
#pragma unroll
            for (int r = 0; r < 4; ++r)
                H1o[(size_t)(m + r) * Hn + n] = acc[mt][nt][r] * (1.0f / 256.0f);
        }
    }
}

// ---------------------------------------------------------------------------
// GEMM mid-fallback (r7-verified; epilogue updated for x16 encoding):
// ws in [147,164) MB.
// ---------------------------------------------------------------------------
constexpr int AH = 0;
constexpr int AL = 8 * 512;
constexpr int BH = 16 * 512;
constexpr int BL = 20 * 512;
constexpr int BUFSZ = 24 * 512;

__global__ __launch_bounds__(256, 2)
void gemm_frag2(const _Float16* __restrict__ Xh, const _Float16* __restrict__ Xl,
                const _Float16* __restrict__ Wh, const _Float16* __restrict__ Wl,
                float* __restrict__ H1)
{
    __shared__ __align__(16) _Float16 S[2 * BUFSZ];

    const int tid = threadIdx.x;
    const int lane = tid & 63;
    const int w = tid >> 6;
    const int nb = blockIdx.x & 15;
    const int mb = blockIdx.x >> 4;
    const int bm4 = mb * 8;
    const int bn4 = nb * 4;
    const int wm = w & 1;
    const int wn = w >> 1;

    auto issue = [&](int ks, int buf) {
        _Float16* base = &S[buf * BUFSZ];
#pragma unroll
        for (int r = 0; r < 2; ++r) {
            const int i = w * 2 + r;
            const size_t ga = ((size_t)(ks * MC + bm4 + i)) * 512 + lane * 8;
            async16(Xh + ga, base + AH + i * 512);
            async16(Xl + ga, base + AL + i * 512);
        }
        const size_t gb = ((size_t)(ks * NC + bn4 + w)) * 512 + lane * 8;
        async16(Wh + gb, base + BH + w * 512);
        async16(Wl + gb, base + BL + w * 512);
    };

    floatx4 acc0[4][2] = {};
    floatx4 acc1[4][2] = {};

    issue(0, 0);
    for (int it = 0; it < KS; ++it) {
        const int buf = it & 1;
        __syncthreads();
        if (it + 1 < KS) issue(it + 1, buf ^ 1);

        const _Float16* base = &S[buf * BUFSZ];
        half8 ah[4], al[4], bh[2], bl[2];
#pragma unroll
        for (int mt = 0; mt < 4; ++mt) {
            ah[mt] = *(const half8*)(base + AH + (wm * 4 + mt) * 512 + lane * 8);
            al[mt] = *(const half8*)(base + AL + (wm * 4 + mt) * 512 + lane * 8);
        }
#pragma unroll
        for (int nt = 0; nt < 2; ++nt) {
            bh[nt] = *(const half8*)(base + BH + (wn * 2 + nt) * 512 + lane * 8);
            bl[nt] = *(const half8*)(base + BL + (wn * 2 + nt) * 512 + lane * 8);
        }
#pragma unroll
        for (int mt = 0; mt < 4; ++mt)
#pragma unroll
            for (int nt = 0; nt < 2; ++nt) {
                acc0[mt][nt] = __builtin_amdgcn_mfma_f32_16x16x32_f16(ah[mt], bh[nt], acc0[mt][nt], 0, 0, 0);
                acc1[mt][nt] = __builtin_amdgcn_mfma_f32_16x16x32_f16(ah[mt], bl[nt], acc1[mt][nt], 0, 0, 0);
                acc1[mt][nt] = __builtin_amdgcn_mfma_f32_16x16x32_f16(al[mt], bh[nt], acc1[mt][nt], 0, 0, 0);
            }
    }

    const int fr = lane & 15;
    const int fq = lane >> 4;
#pragma unroll
    for (int nt = 0; nt < 2; ++nt) {
        const int n = nb * 64 + wn * 32 + nt * 16 + fr;
        if (n >= Hn) continue;
#pragma unroll
        for (int mt = 0; mt < 4; ++mt) {
            const int m = mb * 128 + wm * 64 + mt * 16 + fq * 4;
#pragma unroll
            for (int r = 0; r < 4; ++r)
                H1[(size_t)(m + r) * Hn + n] =
                    (acc0[mt][nt][r] + acc1[mt][nt][r]) * (1.0f / 256.0f);
        }
    }
}

// ---------------------------------------------------------------------------
// GEMM small-ws fallback (r3-verified; self-contained split, unchanged).
// ---------------------------------------------------------------------------
__global__ __launch_bounds__(256, 4)
void gemm_fb(const float* __restrict__ X, const float* __restrict__ W1,
             float* __restrict__ H1)
{
    constexpr int K = Dn;
    constexpr int LD = 72;
    __shared__ __align__(16) _Float16 As[2][64][LD];
    __shared__ __align__(16) _Float16 Bs[2][64][LD];

    const int tid = threadIdx.x;
    const int bm = blockIdx.x * 64;
    const int bn = blockIdx.y * 64;
    const int lane = tid & 63;
    const int wid = tid >> 6;
    const int wm = (wid & 1) * 32;
    const int wn = (wid >> 1) * 32;
    const int fr = lane & 15;
    const int fq = lane >> 4;

    const int row0 = tid >> 3;
    const int row1 = (tid + 256) >> 3;
    const int k8_0 = (tid & 7) * 8;

    float4 rx[2][2], rw[2][2];
    const float zero4[4] = {0.f, 0.f, 0.f, 0.f};

    auto load_tiles = [&](int k0) {
        rx[0][0] = *(const float4*)(X + (size_t)(bm + row0) * K + k0 + k8_0);
        rx[0][1] = *(const float4*)(X + (size_t)(bm + row0) * K + k0 + k8_0 + 4);
        rx[1][0] = *(const float4*)(X + (size_t)(bm + row1) * K + k0 + k8_0);
        rx[1][1] = *(const float4*)(X + (size_t)(bm + row1) * K + k0 + k8_0 + 4);
        const int n0 = bn + row0, n1 = bn + row1;
        if (n0 < Hn) {
            rw[0][0] = *(const float4*)(W1 + (size_t)n0 * K + k0 + k8_0);
            rw[0][1] = *(const float4*)(W1 + (size_t)n0 * K + k0 + k8_0 + 4);
        } else { rw[0][0] = *(const float4*)zero4; rw[0][1] = *(const float4*)zero4; }
        if (n1 < Hn) {
            rw[1][0] = *(const float4*)(W1 + (size_t)n1 * K + k0 + k8_0);
            rw[1][1] = *(const float4*)(W1 + (size_t)n1 * K + k0 + k8_0 + 4);
        } else { rw[1][0] = *(const float4*)zero4; rw[1][1] = *(const float4*)zero4; }
    };

    load_tiles(0);
    floatx4 acc0[2][2] = {};
    floatx4 acc1[2][2] = {};

    for (int k0 = 0; k0 < K; k0 += 64) {
#pragma unroll
        for (int p = 0; p < 2; ++p) {
            const int row = p ? row1 : row0;
            float v[8];
            *(float4*)&v[0] = rx[p][0]; *(float4*)&v[4] = rx[p][1];
            half8 hi, lo;
#pragma unroll
            for (int j = 0; j < 8; ++j) {
                hi[j] = (_Float16)v[j];
                lo[j] = (_Float16)((v[j] - (float)hi[j]) * 4096.0f);
            }
            *(half8*)&As[0][row][k8_0] = hi;
            *(half8*)&As[1][row][k8_0] = lo;

            *(float4*)&v[0] = rw[p][0]; *(float4*)&v[4] = rw[p][1];
#pragma unroll
            for (int j = 0; j < 8; ++j) {
                hi[j] = (_Float16)v[j];
                lo[j] = (_Float16)((v[j] - (float)hi[j]) * 4096.0f);
            }
            *(half8*)&Bs[0][row][k8_0] = hi;
            *(half8*)&Bs[1][row][k8_0] = lo;
        }
        __syncthreads();
        if (k0 + 64 < K) load_tiles(k0 + 64);

#pragma unroll
        for (int c = 0; c < 2; ++c) {
            half8 ahi[2], alo[2], bhi[2], blo[2];
#pragma unroll
            for (int mt = 0; mt < 2; ++mt) {
                ahi[mt] = *(const half8*)&As[0][wm + mt * 16 + fr][c * 32 + fq * 8];
                alo[mt] = *(const half8*)&As[1][wm + mt * 16 + fr][c * 32 + fq * 8];
            }
#pragma unroll
            for (int nt = 0; nt < 2; ++nt) {
                bhi[nt] = *(const half8*)&Bs[0][wn + nt * 16 + fr][c * 32 + fq * 8];
                blo[nt] = *(const half8*)&Bs[1][wn + nt * 16 + fr][c * 32 + fq * 8];
            }
#pragma unroll
            for (int mt = 0; mt < 2; ++mt)
#pragma unroll
                for (int nt = 0; nt < 2; ++nt) {
                    acc0[mt][nt] = __builtin_amdgcn_mfma_f32_16x16x32_f16(ahi[mt], bhi[nt], acc0[mt][nt], 0, 0, 0);
                    acc1[mt][nt] = __builtin_amdgcn_mfma_f32_16x16x32_f16(ahi[mt], blo[nt], acc1[mt][nt], 0, 0, 0);
                    acc1[mt][nt] = __builtin_amdgcn_mfma_f32_16x16x32_f16(alo[mt], bhi[nt], acc1[mt][nt], 0, 0, 0);
                }
        }
        __syncthreads();
    }

#pragma unroll
    for (int nt = 0; nt < 2; ++nt) {
        const int n = bn + wn + nt * 16 + fr;
        if (n >= Hn) continue;
#pragma unroll
        for (int mt = 0; mt < 2; ++mt) {
            const int m = bm + wm + mt * 16 + fq * 4;
#pragma unroll
            for (int r = 0; r < 4; ++r)
                H1[(size_t)(m + r) * Hn + n] =
                    acc0[mt][nt][r] + acc1[mt][nt][r] * (1.0f / 4096.0f);
        }
    }
}

// ---------------------------------------------------------------------------
// LIF scan (r4-r8 verified) + bias add + sum of `split` extra K-partials.
// ---------------------------------------------------------------------------
__global__ __launch_bounds__(1024)
void snn_scan(const float* __restrict__ H1, const float* __restrict__ b1,
              const float* __restrict__ W2, const float* __restrict__ b2,
              float* __restrict__ out, int split)
{
    const int b = blockIdx.x;
    const int tid = threadIdx.x;
    const int lane = tid & 63;
    const int wid = tid >> 6;
    const bool act = (tid < Hn);
    constexpr size_t MH = (size_t)Mn * Hn;

    __shared__ float w2s[1024][5];
    __shared__ unsigned smask[1024];
    __shared__ float h2s[Tn][An];

#pragma unroll
    for (int a = 0; a < An; ++a)
        w2s[tid][a] = act ? W2[a * Hn + tid] : 0.f;

    const float b1v = act ? b1[tid] : 0.f;

    float cur[Tn];
#pragma unroll
    for (int t = 0; t < Tn; ++t) {
        const size_t idx = ((size_t)b * Tn + t) * Hn + tid;
        float c = act ? H1[idx] : 0.f;
        if (act)
            for (int s = 1; s <= split; ++s) c += H1[idx + (size_t)s * MH];
        cur[t] = c + b1v;
    }

    unsigned mask = 0;
    float mem1 = 0.f;
#pragma unroll
    for (int t = 0; t < Tn; ++t) {
        const float reset = (mem1 > 1.0f) ? 1.0f : 0.0f;
        mem1 = (0.99f * mem1 + cur[t]) * (1.0f - reset);
        if (mem1 > 1.0f) mask |= (1u << t);
    }
    smask[tid] = act ? mask : 0u;
    __syncthreads();

#pragma unroll
    for (int tt = 0; tt < 2; ++tt) {
        const int t = wid * 2 + tt;
        float p[An] = {0.f, 0.f, 0.f, 0.f};
        for (int h = lane; h < 1024; h += 64) {
            const float g = (smask[h] >> t) & 1u ? 1.0f : 0.0f;
#pragma unroll
            for (int a = 0; a < An; ++a) p[a] += g * w2s[h][a];
        }
#pragma unroll
        for (int off = 32; off > 0; off >>= 1)
#pragma unroll
            for (int a = 0; a < An; ++a) p[a] += __shfl_down(p[a], off, 64);
        if (lane == 0) {
#pragma unroll
            for (int a = 0; a < An; ++a) h2s[t][a] = p[a];
        }
    }
    __syncthreads();

    if (tid < An) {
        const float bias = b2[tid];
        float mem2 = 0.f;
#pragma unroll
        for (int t = 0; t < Tn; ++t) {
            const float h2 = h2s[t][tid] + bias;
            const float reset = (mem2 > 1.0f) ? 1.0f : 0.0f;
            mem2 = (0.99f * mem2 + h2) * (1.0f - reset);
            out[((size_t)b * Tn + t) * An + tid] = (mem2 > 1.0f) ? 1.0f : 0.0f;
        }
    }
}

extern "C" void kernel_launch(void* const* d_in, const int* in_sizes, int n_in,
                              void* d_out, int out_size, void* d_ws, size_t ws_size,
                              hipStream_t stream) {
    const float* x  = (const float*)d_in[0];   // [B,T,D]
    const float* W1 = (const float*)d_in[1];   // [H,D]
    const float* b1 = (const float*)d_in[2];   // [H]
    const float* W2 = (const float*)d_in[3];   // [A,H]
    const float* b2 = (const float*)d_in[4];   // [A]
    float* out = (float*)d_out;                // [B,T,A]

    char* ws = (char*)d_ws;
    float* H1 = (float*)ws;

    if (ws_size >= WS_SK3) {
        _Float16* Xh = (_Float16*)(ws + 3 * H1_BYTES);
        _Float16* Xl = (_Float16*)(ws + 3 * H1_BYTES + XS_BYTES);
        _Float16* Wh = (_Float16*)(ws + 3 * H1_BYTES + 2 * XS_BYTES);
        _Float16* Wl = (_Float16*)(ws + 3 * H1_BYTES + 2 * XS_BYTES + WSp_BYTES);

        cvt2<<<256 * 25 + 64 * 25, 256, 0, stream>>>(x, W1, Xh, Xl, Wh, Wl);
        gemm_sk3<<<768, 256, 0, stream>>>(Xh, Xl, Wh, Wl, H1);   // bid=((mb*8)+nb)*3+kh
        snn_scan<<<Bn, 1024, 0, stream>>>(H1, b1, W2, b2, out, 2);
    } else if (ws_size >= WS_SPLITK) {
        _Float16* Xh = (_Float16*)(ws + 2 * H1_BYTES);
        _Float16* Xl = (_Float16*)(ws + 2 * H1_BYTES + XS_BYTES);
        _Float16* Wh = (_Float16*)(ws + 2 * H1_BYTES + 2 * XS_BYTES);
        _Float16* Wl = (_Float16*)(ws + 2 * H1_BYTES + 2 * XS_BYTES + WSp_BYTES);

        cvt2<<<256 * 25 + 64 * 25, 256, 0, stream>>>(x, W1, Xh, Xl, Wh, Wl);
        gemm_sk2<<<512, 256, 0, stream>>>(Xh, Xl, Wh, Wl, H1);   // kh=&1, nb=(>>1)&7, mb=>>4
        snn_scan<<<Bn, 1024, 0, stream>>>(H1, b1, W2, b2, out, 1);
    } else if (ws_size >= WS_R7) {
        _Float16* Xh = (_Float16*)(ws + H1_BYTES);
        _Float16* Xl = (_Float16*)(ws + H1_BYTES + XS_BYTES);
        _Float16* Wh = (_Float16*)(ws + H1_BYTES + 2 * XS_BYTES);
        _Float16* Wl = (_Float16*)(ws + H1_BYTES + 2 * XS_BYTES + WSp_BYTES);

        cvt2<<<256 * 25 + 64 * 25, 256, 0, stream>>>(x, W1, Xh, Xl, Wh, Wl);
        gemm_frag2<<<512, 256, 0, stream>>>(Xh, Xl, Wh, Wl, H1);
        snn_scan<<<Bn, 1024, 0, stream>>>(H1, b1, W2, b2, out, 0);
    } else {
        dim3 grid(Mn / 64, (Hn + 63) / 64);
        gemm_fb<<<grid, 256, 0, stream>>>(x, W1, H1);
        snn_scan<<<Bn, 1024, 0, stream>>>(H1, b1, W2, b2, out, 0);
    }
}

// Round 9
// 367.146 us; speedup vs baseline: 1.0311x; 1.0311x over previous
//
#include <hip/hip_runtime.h>
#include <hip/hip_bf16.h>

// Problem constants (fixed by reference setup_inputs)
constexpr int Bn = 128;   // batch
constexpr int Tn = 32;    // timesteps
constexpr int Dn = 6400;  // input dim (K)
constexpr int Hn = 1000;  // hidden  (N)
constexpr int An = 4;     // actions
constexpr int Mn = Bn * Tn;   // 4096 GEMM rows
constexpr int Npad = 1024;    // W rows padded -> no N-guards in GEMM

constexpr int KS = Dn / 32;   // 200 k-chunks of 32
constexpr int MC = Mn / 16;   // 256 m-chunks of 16 rows
constexpr int NC = Npad / 16; // 64  n-chunks of 16 rows

typedef _Float16 half8 __attribute__((ext_vector_type(8)));
typedef _Float16 half4 __attribute__((ext_vector_type(4)));
typedef float floatx4 __attribute__((ext_vector_type(4)));

// Workspace layouts (bytes)
constexpr size_t H1_BYTES  = (size_t)Mn * Hn * 4;       // 16,384,000
constexpr size_t XS_BYTES  = (size_t)Mn * Dn * 2;       // per split
constexpr size_t WSp_BYTES = (size_t)Npad * Dn * 2;     // per split
constexpr size_t WS_R7     = H1_BYTES + 2 * XS_BYTES + 2 * WSp_BYTES;      // 147,456,000
constexpr size_t WS_SPLITK = 2 * H1_BYTES + 2 * XS_BYTES + 2 * WSp_BYTES;  // 163,840,000

__device__ __forceinline__ void async16(const void* g, void* l) {
    __builtin_amdgcn_global_load_lds(
        (const __attribute__((address_space(1))) void*)g,
        (__attribute__((address_space(3))) void*)l, 16, 0, 0);
}

// ---------------------------------------------------------------------------
// Pre-pass: fp16 hi/lo split into fragment-chunk layout, both sides 1KB
// coalesced via LDS transpose.
// r12 encoding (verified absmax=0): values pre-scaled by 16 (exact exponent
// shift), lo stored UNSCALED: hi = fp16(16*v), lo = fp16(16*v - hi).  All
// three MFMA products (hi*hi, hi*lo, lo*hi) carry coefficient 1 -> single
// accumulator in the GEMM; epilogue multiplies by 1/256.
// ---------------------------------------------------------------------------
__global__ __launch_bounds__(256)
void cvt2(const float* __restrict__ X, const float* __restrict__ W1,
          _Float16* __restrict__ Xh, _Float16* __restrict__ Xl,
          _Float16* __restrict__ Wh, _Float16* __restrict__ Wl)
{
    constexpr int LD2 = 264;
    __shared__ __align__(16) _Float16 hiS[16][LD2];
    __shared__ __align__(16) _Float16 loS[16][LD2];

    const int tid = threadIdx.x;
    const int lane = tid & 63;
    const int w = tid >> 6;
    const int bx = blockIdx.x;

    const float* src;
    _Float16 *dh, *dl;
    int c4, ks0, crow, nrows;
    if (bx < 256 * 25) {                       // X part
        c4 = bx & 255; ks0 = (bx >> 8) * 8;
        src = X; dh = Xh; dl = Xl; crow = MC; nrows = 16;
    } else {                                   // W part (rows >= Hn zeroed)
        const int b2 = bx - 256 * 25;
        c4 = b2 & 63; ks0 = (b2 >> 6) * 8;
        src = W1; dh = Wh; dl = Wl; crow = NC; nrows = Hn - c4 * 16;
    }

#pragma unroll
    for (int j = 0; j < 4; ++j) {
        const int row = w * 4 + j;
        float4 v = make_float4(0.f, 0.f, 0.f, 0.f);
        if (row < nrows)
            v = *(const float4*)(src + (size_t)(c4 * 16 + row) * Dn + ks0 * 32 + lane * 4);
        half4 hi, lo;
        const float vx = v.x * 16.0f, vy = v.y * 16.0f,
                    vz = v.z * 16.0f, vw = v.w * 16.0f;
        hi[0] = (_Float16)vx; lo[0] = (_Float16)(vx - (float)hi[0]);
        hi[1] = (_Float16)vy; lo[1] = (_Float16)(vy - (float)hi[1]);
        hi[2] = (_Float16)vz; lo[2] = (_Float16)(vz - (float)hi[2]);
        hi[3] = (_Float16)vw; lo[3] = (_Float16)(vw - (float)hi[3]);
        *(half4*)&hiS[row][lane * 4] = hi;
        *(half4*)&loS[row][lane * 4] = lo;
    }
    __syncthreads();

    const int lr = lane & 15, lg = lane >> 4;
#pragma unroll
    for (int q = 0; q < 2; ++q) {
        const int ks = w * 2 + q;
        const size_t cbase = ((size_t)(ks0 + ks) * crow + c4) * 512;
        const half8 h = *(const half8*)&hiS[lr][ks * 32 + lg * 8];
        const half8 l = *(const half8*)&loS[lr][ks * 32 + lg * 8];
        *(half8*)(dh + cbase + lane * 8) = h;
        *(half8*)(dl + cbase + lane * 8) = l;
    }
}

// ---------------------------------------------------------------------------
// GEMM primary (r16 "gemm_ph"): 256x128 tile, 512 threads, 1 block/CU,
// 4-phase schedule (m201-template shape), split-K=2.
//
// Post-mortem chain: six schedules at 1-barrier-per-K-chunk granularity
// (r8/r9/r11/r12/r14 @2 blocks/CU, r15 @3 blocks/CU) pinned at 50-54% / 33%.
// Occupancy is NOT the lever (r15 regressed; m201 hits 62% at 2 waves/SIMD).
// The proven lever is the PHASE-SPLIT schedule (m196->m198->m201 +28-41%):
// split each K-chunk into 4 phases, each {future loads || ds_read next
// A-frag -> barrier -> 12 MFMA}, counted vmcnt so staging spans phases.
// Each load gets one phase of MFMA shadow; per-phase barriers keep the
// block's 8 waves handing the MFMA pipe off instead of bunching.
//
// Geometry: 8 waves (wm=w>>1 in 0..3, wn=w&1), wave tile 64x64, acc[4][4]
// where acc[p] = m-chunk wm*4+p.  Phase p computes mt=p (12 MFMA: 3 hi/lo
// passes x 4 nt).  A-frag for (it,p) was ds_read at phase p-1 (wrap: (it,0)
// read at (it-1,3) from the next LDS buffer).
// LDS: 4-buffer rotation, 4 x 32 KB = 128 KB -> occupancy 1 block/CU
// guaranteed (no spill pressure; allocator may use up to 256 VGPRs).
// DMA 2 chunks ahead.  B: direct global->reg, hi loaded at p0, lo at p1,
// double-buffered per chunk (alternates by it&1; NIT=100=4*25, no tail).
//
// vmcnt audit (FIFO, m135): per chunk the vmem order is
//   [p0: Bh(it+1) x4][p1: Bl(it+1) x4, DMA(it+2) x4].
// At (it,p3) the newest 12 = {Bh(it+1),Bl(it+1),DMA(it+2)} -> vmcnt(12)
// retires DMA(it+1) before ds_read of buf((it+1)&3); barrier makes it
// cross-wave.  Never drains to 0.  Buffer overwrite: DMA(it+2) hits
// buf((it+2)&3) whose last reader finished 2+ barriers earlier.
// Prologue: DMA(0),DMA(1),B(0) -> vmcnt(12) retires DMA(0).
// ---------------------------------------------------------------------------
__global__ __launch_bounds__(512, 1)
void gemm_ph(const _Float16* __restrict__ Xh, const _Float16* __restrict__ Xl,
             const _Float16* __restrict__ Wh, const _Float16* __restrict__ Wl,
             float* __restrict__ H1)
{
    __shared__ __align__(16) _Float16 S[4][32][512];   // 128 KB

    const int tid = threadIdx.x;
    const int lane = tid & 63;
    const int w = tid >> 6;                // 0..7
    const int kh = blockIdx.x & 1;
    const int nb = (blockIdx.x >> 1) & 7;
    const int mb = blockIdx.x >> 4;        // 0..15
    const int bm16 = mb * 16;              // base m-chunk (16 chunks/block)
    const int bn8 = nb * 8;                // base n-chunk (8 chunks/block)
    const int wm = w >> 1;                 // 0..3
    const int wn = w & 1;                  // 0..1
    const int ks0 = kh * (KS / 2);
    constexpr int NIT = KS / 2;            // 100 = 4*25 (no tail)

    // A staging: wave w stages hi+lo of m-chunks 2w, 2w+1 (4 async16/wave,
    // 32/block = 32 KB per chunk).
    auto issueA = [&](int ks, int buf) {
        _Float16* base = &S[buf][0][0];
#pragma unroll
        for (int r = 0; r < 2; ++r) {
            const int i = w * 2 + r;       // 0..15
            const size_t ga = ((size_t)(ks * MC + bm16 + i)) * 512 + lane * 8;
            async16(Xh + ga, base + (0 + i) * 512);
            async16(Xl + ga, base + (16 + i) * 512);
        }
    };

    // B fragments: direct global->VGPR, lane-contiguous 1 KB per instruction.
    const _Float16* bhp = Wh + ((size_t)(ks0 * NC + bn8 + wn * 4)) * 512 + lane * 8;
    const _Float16* blp = Wl + ((size_t)(ks0 * NC + bn8 + wn * 4)) * 512 + lane * 8;
    constexpr size_t BSTEP = (size_t)NC * 512;

    floatx4 acc[4][4] = {};                // [mt=phase][nt]

    half8 bh0[4], bl0[4], bh1[4], bl1[4];  // B per-chunk double buffer
    half8 aaH, aaL, abH, abL;              // A frag rotation (2 sets)

    // prologue: DMA(0)->buf0, DMA(1)->buf1, B(0)->set0.
    // vmcnt(12): outstanding = DMA0(4)+DMA1(4)+B0(8)=16 -> retires DMA0.
    issueA(ks0 + 0, 0);
    issueA(ks0 + 1, 1);
#pragma unroll
    for (int nt = 0; nt < 4; ++nt) bh0[nt] = *(const half8*)(bhp + nt * 512);
#pragma unroll
    for (int nt = 0; nt < 4; ++nt) bl0[nt] = *(const half8*)(blp + nt * 512);
    asm volatile("s_waitcnt vmcnt(12)" ::: "memory");
    __builtin_amdgcn_sched_barrier(0);
    __builtin_amdgcn_s_barrier();
    __builtin_amdgcn_sched_barrier(0);
    aaH = *(const half8*)&S[0][wm * 4 + 0][lane * 8];
    aaL = *(const half8*)&S[0][16 + wm * 4 + 0][lane * 8];

    // Phase macro.  P consumes (ACURH,ACURL) = A(IT,P); reads next A frag
    // into (ANXH,ANXL); 12 MFMA on acc[P] with B-set C.
#define PH(IT, BUF, P, ACURH, ACURL, ANXH, ANXL, BCH, BCL, BNH, BNL, DO_VM)     \
    {                                                                           \
        if (DO_VM) asm volatile("s_waitcnt vmcnt(12)" ::: "memory");            \
        __builtin_amdgcn_sched_barrier(0);                                      \
        __builtin_amdgcn_s_barrier();                                           \
        __builtin_amdgcn_sched_barrier(0);                                      \
        if ((P) == 0 && (IT) + 1 < NIT) {                                       \
            const size_t bo = (size_t)((IT) + 1) * BSTEP;                       \
            _Pragma("unroll")                                                   \
            for (int nt2 = 0; nt2 < 4; ++nt2)                                   \
                BNH[nt2] = *(const half8*)(bhp + bo + nt2 * 512);               \
        }                                                                       \
        if ((P) == 1) {                                                         \
            if ((IT) + 1 < NIT) {                                               \
                const size_t bo = (size_t)((IT) + 1) * BSTEP;                   \
                _Pragma("unroll")                                               \
                for (int nt2 = 0; nt2 < 4; ++nt2)                               \
                    BNL[nt2] = *(const half8*)(blp + bo + nt2 * 512);           \
            }                                                                   \
            if ((IT) + 2 < NIT) issueA(ks0 + (IT) + 2, ((IT) + 2) & 3);         \
        }                                                                       \
        if ((P) < 3) {                                                          \
            ANXH = *(const half8*)&S[BUF][wm * 4 + (P) + 1][lane * 8];          \
            ANXL = *(const half8*)&S[BUF][16 + wm * 4 + (P) + 1][lane * 8];     \
        } else if ((IT) + 1 < NIT) {                                            \
            ANXH = *(const half8*)&S[((IT) + 1) & 3][wm * 4 + 0][lane * 8];     \
            ANXL = *(const half8*)&S[((IT) + 1) & 3][16 + wm * 4 + 0][lane * 8];\
        }                                                                       \
        __builtin_amdgcn_sched_barrier(0);                                      \
        __builtin_amdgcn_s_setprio(1);                                          \
        _Pragma("unroll")                                                       \
        for (int nt2 = 0; nt2 < 4; ++nt2)                                       \
            acc[P][nt2] = __builtin_amdgcn_mfma_f32_16x16x32_f16(ACURH, BCH[nt2], acc[P][nt2], 0, 0, 0); \
        _Pragma("unroll")                                                       \
        for (int nt2 = 0; nt2 < 4; ++nt2)                                       \
            acc[P][nt2] = __builtin_amdgcn_mfma_f32_16x16x32_f16(ACURH, BCL[nt2], acc[P][nt2], 0, 0, 0); \
        _Pragma("unroll")                                                       \
        for (int nt2 = 0; nt2 < 4; ++nt2)                                       \
            acc[P][nt2] = __builtin_amdgcn_mfma_f32_16x16x32_f16(ACURL, BCH[nt2], acc[P][nt2], 0, 0, 0); \
        __builtin_amdgcn_s_setprio(0);                                          \
    }

    // Chunk = 4 phases; A sets alternate per phase (even count -> invariant:
    // chunk entry has A(it,0) in aa).  B sets alternate per chunk.
#define CHUNK(IT, BUF, BCH, BCL, BNH, BNL)                                      \
    PH(IT, BUF, 0, aaH, aaL, abH, abL, BCH, BCL, BNH, BNL, 0)                   \
    PH(IT, BUF, 1, abH, abL, aaH, aaL, BCH, BCL, BNH, BNL, 0)                   \
    PH(IT, BUF, 2, aaH, aaL, abH, abL, BCH, BCL, BNH, BNL, 0)                   \
    PH(IT, BUF, 3, abH, abL, aaH, aaL, BCH, BCL, BNH, BNL, 1)

    for (int it = 0; it < NIT; it += 4) {
        CHUNK(it + 0, 0, bh0, bl0, bh1, bl1);
        CHUNK(it + 1, 1, bh1, bl1, bh0, bl0);
        CHUNK(it + 2, 2, bh0, bl0, bh1, bl1);
        CHUNK(it + 3, 3, bh1, bl1, bh0, bl0);
    }
#undef CHUNK
#undef PH

    // epilogue (no bias -- scan adds b1): C/D col=lane&15, row=(lane>>4)*4+r
    // x16 pre-scale on both operands -> result carries 256x; undo here.
    float* H1o = H1 + (size_t)kh * ((size_t)Mn * Hn);
    const int fr = lane & 15;
    const int fq = lane >> 4;
#pragma unroll
    for (int nt = 0; nt < 4; ++nt) {
        const int n = nb * 128 + wn * 64 + nt * 16 + fr;
        if (n >= Hn) continue;
#pragma unroll
        for (int mt = 0; mt < 4; ++mt) {
            const int m = mb * 256 + wm * 64 + mt * 16 + fq * 4;
#pragma unroll
            for (int r = 0; r < 4; ++r)
                H1o[(size_t)(m + r) * Hn + n] = acc[mt][nt][r] * (1.0f / 256.0f);
        }
    }
}

// ---------------------------------------------------------------------------
// GEMM split-K=2 fallback (r11-structure, ~139 us verified class): kept as
// safety net -- unused while ws >= WS_SPLITK routes to gemm_ph.
// ---------------------------------------------------------------------------
__global__ __launch_bounds__(256, 2)
void gemm_sk2(const _Float16* __restrict__ Xh, const _Float16* __restrict__ Xl,
              const _Float16* __restrict__ Wh, const _Float16* __restrict__ Wl,
              float* __restrict__ H1)
{
    __shared__ __align__(16) _Float16 S[4][16][512];   // 64 KB

    const int tid = threadIdx.x;
    const int lane = tid & 63;
    const int w = tid >> 6;
    const int kh = blockIdx.x & 1;
    const int nb = (blockIdx.x >> 1) & 7;
    const int mb = blockIdx.x >> 4;
    const int bm8 = mb * 8;
    const int bn8 = nb * 8;
    const int wm = w & 1;
    const int wn = w >> 1;
    const int ks0 = kh * (KS / 2);
    constexpr int NIT = KS / 2;                // 100 (even)

    auto issueA = [&](int ks, int buf) {
        _Float16* base = &S[buf][0][0];
#pragma unroll
        for (int r = 0; r < 2; ++r) {
            const int i = w * 2 + r;
            const size_t ga = ((size_t)(ks * MC + bm8 + i)) * 512 + lane * 8;
            async16(Xh + ga, base + (0 + i) * 512);
            async16(Xl + ga, base + (8 + i) * 512);
        }
    };

    const _Float16* bhp = Wh + ((size_t)(ks0 * NC + bn8 + wn * 4)) * 512 + lane * 8;
    const _Float16* blp = Wl + ((size_t)(ks0 * NC + bn8 + wn * 4)) * 512 + lane * 8;
    constexpr size_t BSTEP = (size_t)NC * 512;

    floatx4 acc[4][4] = {};

    issueA(ks0 + 0, 0);
    issueA(ks0 + 1, 1);

#define SK2_BODY(IT, BUF)                                                       \
    {                                                                           \
        asm volatile("s_waitcnt vmcnt(4)" ::: "memory");                        \
        __builtin_amdgcn_sched_barrier(0);                                      \
        __builtin_amdgcn_s_barrier();                                           \
        __builtin_amdgcn_sched_barrier(0);                                      \
        half8 bh[4], bl[4];                                                     \
        {                                                                       \
            const size_t bo = (size_t)(IT) * BSTEP;                             \
            _Pragma("unroll")                                                   \
            for (int nt = 0; nt < 4; ++nt) {                                    \
                bh[nt] = *(const half8*)(bhp + bo + nt * 512);                  \
                bl[nt] = *(const half8*)(blp + bo + nt * 512);                  \
            }                                                                   \
        }                                                                       \
        __builtin_amdgcn_sched_barrier(0);                                      \
        if ((IT) + 2 < NIT) issueA(ks0 + (IT) + 2, ((IT) + 2) & 3);             \
        __builtin_amdgcn_sched_barrier(0);                                      \
        half8 ah[4], al[4];                                                     \
        _Pragma("unroll")                                                       \
        for (int mt = 0; mt < 4; ++mt) {                                        \
            ah[mt] = *(const half8*)&S[BUF][wm * 4 + mt][lane * 8];             \
            al[mt] = *(const half8*)&S[BUF][8 + wm * 4 + mt][lane * 8];         \
        }                                                                       \
        _Pragma("unroll")                                                       \
        for (int mt = 0; mt < 4; ++mt)                                          \
            _Pragma("unroll")                                                   \
            for (int nt = 0; nt < 4; ++nt)                                      \
                acc[mt][nt] = __builtin_amdgcn_mfma_f32_16x16x32_f16(ah[mt], bh[nt], acc[mt][nt], 0, 0, 0); \
        _Pragma("unroll")                                                       \
        for (int mt = 0; mt < 4; ++mt)                                          \
            _Pragma("unroll")                                                   \
            for (int nt = 0; nt < 4; ++nt)                                      \
                acc[mt][nt] = __builtin_amdgcn_mfma_f32_16x16x32_f16(ah[mt], bl[nt], acc[mt][nt], 0, 0, 0); \
        _Pragma("unroll")                                                       \
        for (int mt = 0; mt < 4; ++mt)                                          \
            _Pragma("unroll")                                                   \
            for (int nt = 0; nt < 4; ++nt)                                      \
                acc[mt][nt] = __builtin_amdgcn_mfma_f32_16x16x32_f16(al[mt], bh[nt], acc[mt][nt], 0, 0, 0); \
    }

    for (int it = 0; it < NIT; it += 4) {
        SK2_BODY(it + 0, 0);
        SK2_BODY(it + 1, 1);
        SK2_BODY(it + 2, 2);
        SK2_BODY(it + 3, 3);
    }
#undef SK2_BODY

    float* H1o = H1 + (size_t)kh * ((size_t)Mn * Hn);
    const int fr = lane & 15;
    const int fq = lane >> 4;
#pragma unroll
    for (int nt = 0; nt < 4; ++nt) {
        const int n = nb * 128 + wn * 64 + nt * 16 + fr;
        if (n >= Hn) continue;
#pragma unroll
        for (int mt = 0; mt < 4; ++mt) {
            const int m = mb * 128 + wm * 64 + mt * 16 + fq * 4;
#pragma unroll
            for (int r = 0; r < 4; ++r)
                H1o[(size_t)(m + r) * Hn + n] = acc[mt][nt][r] * (1.0f / 256.0f);
        }
    }
}

// ---------------------------------------------------------------------------
// GEMM mid-fallback (r7-verified; epilogue updated for x16 encoding):
// ws in [147,164) MB.
// ---------------------------------------------------------------------------
constexpr int AH = 0;
constexpr int AL = 8 * 512;
constexpr int BH = 16 * 512;
constexpr int BL = 20 * 512;
constexpr int BUFSZ = 24 * 512;

__global__ __launch_bounds__(256, 2)
void gemm_frag2(const _Float16* __restrict__ Xh, const _Float16* __restrict__ Xl,
                const _Float16* __restrict__ Wh, const _Float16* __restrict__ Wl,
                float* __restrict__ H1)
{
    __shared__ __align__(16) _Float16 S[2 * BUFSZ];

    const int tid = threadIdx.x;
    const int lane = tid & 63;
    const int w = tid >> 6;
    const int nb = blockIdx.x & 15;
    const int mb = blockIdx.x >> 4;
    const int bm4 = mb * 8;
    const int bn4 = nb * 4;
    const int wm = w & 1;
    const int wn = w >> 1;

    auto issue = [&](int ks, int buf) {
        _Float16* base = &S[buf * BUFSZ];
#pragma unroll
        for (int r = 0; r < 2; ++r) {
            const int i = w * 2 + r;
            const size_t ga = ((size_t)(ks * MC + bm4 + i)) * 512 + lane * 8;
            async16(Xh + ga, base + AH + i * 512);
            async16(Xl + ga, base + AL + i * 512);
        }
        const size_t gb = ((size_t)(ks * NC + bn4 + w)) * 512 + lane * 8;
        async16(Wh + gb, base + BH + w * 512);
        async16(Wl + gb, base + BL + w * 512);
    };

    floatx4 acc0[4][2] = {};
    floatx4 acc1[4][2] = {};

    issue(0, 0);
    for (int it = 0; it < KS; ++it) {
        const int buf = it & 1;
        __syncthreads();
        if (it + 1 < KS) issue(it + 1, buf ^ 1);

        const _Float16* base = &S[buf * BUFSZ];
        half8 ah[4], al[4], bh[2], bl[2];
#pragma unroll
        for (int mt = 0; mt < 4; ++mt) {
            ah[mt] = *(const half8*)(base + AH + (wm * 4 + mt) * 512 + lane * 8);
            al[mt] = *(const half8*)(base + AL + (wm * 4 + mt) * 512 + lane * 8);
        }
#pragma unroll
        for (int nt = 0; nt < 2; ++nt) {
            bh[nt] = *(const half8*)(base + BH + (wn * 2 + nt) * 512 + lane * 8);
            bl[nt] = *(const half8*)(base + BL + (wn * 2 + nt) * 512 + lane * 8);
        }
#pragma unroll
        for (int mt = 0; mt < 4; ++mt)
#pragma unroll
            for (int nt = 0; nt < 2; ++nt) {
                acc0[mt][nt] = __builtin_amdgcn_mfma_f32_16x16x32_f16(ah[mt], bh[nt], acc0[mt][nt], 0, 0, 0);
                acc1[mt][nt] = __builtin_amdgcn_mfma_f32_16x16x32_f16(ah[mt], bl[nt], acc1[mt][nt], 0, 0, 0);
                acc1[mt][nt] = __builtin_amdgcn_mfma_f32_16x16x32_f16(al[mt], bh[nt], acc1[mt][nt], 0, 0, 0);
            }
    }

    const int fr = lane & 15;
    const int fq = lane >> 4;
#pragma unroll
    for (int nt = 0; nt < 2; ++nt) {
        const int n = nb * 64 + wn * 32 + nt * 16 + fr;
        if (n >= Hn) continue;
#pragma unroll
        for (int mt = 0; mt < 4; ++mt) {
            const int m = mb * 128 + wm * 64 + mt * 16 + fq * 4;
#pragma unroll
            for (int r = 0; r < 4; ++r)
                H1[(size_t)(m + r) * Hn + n] =
                    (acc0[mt][nt][r] + acc1[mt][nt][r]) * (1.0f / 256.0f);
        }
    }
}

// ---------------------------------------------------------------------------
// GEMM small-ws fallback (r3-verified; self-contained split, unchanged).
// ---------------------------------------------------------------------------
__global__ __launch_bounds__(256, 4)
void gemm_fb(const float* __restrict__ X, const float* __restrict__ W1,
             float* __restrict__ H1)
{
    constexpr int K = Dn;
    constexpr int LD = 72;
    __shared__ __align__(16) _Float16 As[2][64][LD];
    __shared__ __align__(16) _Float16 Bs[2][64][LD];

    const int tid = threadIdx.x;
    const int bm = blockIdx.x * 64;
    const int bn = blockIdx.y * 64;
    const int lane = tid & 63;
    const int wid = tid >> 6;
    const int wm = (wid & 1) * 32;
    const int wn = (wid >> 1) * 32;
    const int fr = lane & 15;
    const int fq = lane >> 4;

    const int row0 = tid >> 3;
    const int row1 = (tid + 256) >> 3;
    const int k8_0 = (tid & 7) * 8;

    float4 rx[2][2], rw[2][2];
    const float zero4[4] = {0.f, 0.f, 0.f, 0.f};

    auto load_tiles = [&](int k0) {
        rx[0][0] = *(const float4*)(X + (size_t)(bm + row0) * K + k0 + k8_0);
        rx[0][1] = *(const float4*)(X + (size_t)(bm + row0) * K + k0 + k8_0 + 4);
        rx[1][0] = *(const float4*)(X + (size_t)(bm + row1) * K + k0 + k8_0);
        rx[1][1] = *(const float4*)(X + (size_t)(bm + row1) * K + k0 + k8_0 + 4);
        const int n0 = bn + row0, n1 = bn + row1;
        if (n0 < Hn) {
            rw[0][0] = *(const float4*)(W1 + (size_t)n0 * K + k0 + k8_0);
            rw[0][1] = *(const float4*)(W1 + (size_t)n0 * K + k0 + k8_0 + 4);
        } else { rw[0][0] = *(const float4*)zero4; rw[0][1] = *(const float4*)zero4; }
        if (n1 < Hn) {
            rw[1][0] = *(const float4*)(W1 + (size_t)n1 * K + k0 + k8_0);
            rw[1][1] = *(const float4*)(W1 + (size_t)n1 * K + k0 + k8_0 + 4);
        } else { rw[1][0] = *(const float4*)zero4; rw[1][1] = *(const float4*)zero4; }
    };

    load_tiles(0);
    floatx4 acc0[2][2] = {};
    floatx4 acc1[2][2] = {};

    for (int k0 = 0; k0 < K; k0 += 64) {
#pragma unroll
        for (int p = 0; p < 2; ++p) {
            const int row = p ? row1 : row0;
            float v[8];
            *(float4*)&v[0] = rx[p][0]; *(float4*)&v[4] = rx[p][1];
            half8 hi, lo;
#pragma unroll
            for (int j = 0; j < 8; ++j) {
                hi[j] = (_Float16)v[j];
                lo[j] = (_Float16)((v[j] - (float)hi[j]) * 4096.0f);
            }
            *(half8*)&As[0][row][k8_0] = hi;
            *(half8*)&As[1][row][k8_0] = lo;

            *(float4*)&v[0] = rw[p][0]; *(float4*)&v[4] = rw[p][1];
#pragma unroll
            for (int j = 0; j < 8; ++j) {
                hi[j] = (_Float16)v[j];
                lo[j] = (_Float16)((v[j] - (float)hi[j]) * 4096.0f);
            }
            *(half8*)&Bs[0][row][k8_0] = hi;
            *(half8*)&Bs[1][row][k8_0] = lo;
        }
        __syncthreads();
        if (k0 + 64 < K) load_tiles(k0 + 64);

#pragma unroll
        for (int c = 0; c < 2; ++c) {
            half8 ahi[2], alo[2], bhi[2], blo[2];
#pragma unroll
            for (int mt = 0; mt < 2; ++mt) {
                ahi[mt] = *(const half8*)&As[0][wm + mt * 16 + fr][c * 32 + fq * 8];
                alo[mt] = *(const half8*)&As[1][wm + mt * 16 + fr][c * 32 + fq * 8];
            }
#pragma unroll
            for (int nt = 0; nt < 2; ++nt) {
                bhi[nt] = *(const half8*)&Bs[0][wn + nt * 16 + fr][c * 32 + fq * 8];
                blo[nt] = *(const half8*)&Bs[1][wn + nt * 16 + fr][c * 32 + fq * 8];
            }
#pragma unroll
            for (int mt = 0; mt < 2; ++mt)
#pragma unroll
                for (int nt = 0; nt < 2; ++nt) {
                    acc0[mt][nt] = __builtin_amdgcn_mfma_f32_16x16x32_f16(ahi[mt], bhi[nt], acc0[mt][nt], 0, 0, 0);
                    acc1[mt][nt] = __builtin_amdgcn_mfma_f32_16x16x32_f16(ahi[mt], blo[nt], acc1[mt][nt], 0, 0, 0);
                    acc1[mt][nt] = __builtin_amdgcn_mfma_f32_16x16x32_f16(alo[mt], bhi[nt], acc1[mt][nt], 0, 0, 0);
                }
        }
        __syncthreads();
    }

#pragma unroll
    for (int nt = 0; nt < 2; ++nt) {
        const int n = bn + wn + nt * 16 + fr;
        if (n >= Hn) continue;
#pragma unroll
        for (int mt = 0; mt < 2; ++mt) {
            const int m = bm + wm + mt * 16 + fq * 4;
#pragma unroll
            for (int r = 0; r < 4; ++r)
                H1[(size_t)(m + r) * Hn + n] =
                    acc0[mt][nt][r] + acc1[mt][nt][r] * (1.0f / 4096.0f);
        }
    }
}

// ---------------------------------------------------------------------------
// LIF scan (r4-r8 verified) + bias add + sum of `split` extra K-partials.
// ---------------------------------------------------------------------------
__global__ __launch_bounds__(1024)
void snn_scan(const float* __restrict__ H1, const float* __restrict__ b1,
              const float* __restrict__ W2, const float* __restrict__ b2,
              float* __restrict__ out, int split)
{
    const int b = blockIdx.x;
    const int tid = threadIdx.x;
    const int lane = tid & 63;
    const int wid = tid >> 6;
    const bool act = (tid < Hn);
    constexpr size_t MH = (size_t)Mn * Hn;

    __shared__ float w2s[1024][5];
    __shared__ unsigned smask[1024];
    __shared__ float h2s[Tn][An];

#pragma unroll
    for (int a = 0; a < An; ++a)
        w2s[tid][a] = act ? W2[a * Hn + tid] : 0.f;

    const float b1v = act ? b1[tid] : 0.f;

    float cur[Tn];
#pragma unroll
    for (int t = 0; t < Tn; ++t) {
        const size_t idx = ((size_t)b * Tn + t) * Hn + tid;
        float c = act ? H1[idx] : 0.f;
        if (act)
            for (int s = 1; s <= split; ++s) c += H1[idx + (size_t)s * MH];
        cur[t] = c + b1v;
    }

    unsigned mask = 0;
    float mem1 = 0.f;
#pragma unroll
    for (int t = 0; t < Tn; ++t) {
        const float reset = (mem1 > 1.0f) ? 1.0f : 0.0f;
        mem1 = (0.99f * mem1 + cur[t]) * (1.0f - reset);
        if (mem1 > 1.0f) mask |= (1u << t);
    }
    smask[tid] = act ? mask : 0u;
    __syncthreads();

#pragma unroll
    for (int tt = 0; tt < 2; ++tt) {
        const int t = wid * 2 + tt;
        float p[An] = {0.f, 0.f, 0.f, 0.f};
        for (int h = lane; h < 1024; h += 64) {
            const float g = (smask[h] >> t) & 1u ? 1.0f : 0.0f;
#pragma unroll
            for (int a = 0; a < An; ++a) p[a] += g * w2s[h][a];
        }
#pragma unroll
        for (int off = 32; off > 0; off >>= 1)
#pragma unroll
            for (int a = 0; a < An; ++a) p[a] += __shfl_down(p[a], off, 64);
        if (lane == 0) {
#pragma unroll
            for (int a = 0; a < An; ++a) h2s[t][a] = p[a];
        }
    }
    __syncthreads();

    if (tid < An) {
        const float bias = b2[tid];
        float mem2 = 0.f;
#pragma unroll
        for (int t = 0; t < Tn; ++t) {
            const float h2 = h2s[t][tid] + bias;
            const float reset = (mem2 > 1.0f) ? 1.0f : 0.0f;
            mem2 = (0.99f * mem2 + h2) * (1.0f - reset);
            out[((size_t)b * Tn + t) * An + tid] = (mem2 > 1.0f) ? 1.0f : 0.0f;
        }
    }
}

extern "C" void kernel_launch(void* const* d_in, const int* in_sizes, int n_in,
                              void* d_out, int out_size, void* d_ws, size_t ws_size,
                              hipStream_t stream) {
    const float* x  = (const float*)d_in[0];   // [B,T,D]
    const float* W1 = (const float*)d_in[1];   // [H,D]
    const float* b1 = (const float*)d_in[2];   // [H]
    const float* W2 = (const float*)d_in[3];   // [A,H]
    const float* b2 = (const float*)d_in[4];   // [A]
    float* out = (float*)d_out;                // [B,T,A]

    char* ws = (char*)d_ws;
    float* H1 = (float*)ws;

    if (ws_size >= WS_SPLITK) {
        _Float16* Xh = (_Float16*)(ws + 2 * H1_BYTES);
        _Float16* Xl = (_Float16*)(ws + 2 * H1_BYTES + XS_BYTES);
        _Float16* Wh = (_Float16*)(ws + 2 * H1_BYTES + 2 * XS_BYTES);
        _Float16* Wl = (_Float16*)(ws + 2 * H1_BYTES + 2 * XS_BYTES + WSp_BYTES);

        cvt2<<<256 * 25 + 64 * 25, 256, 0, stream>>>(x, W1, Xh, Xl, Wh, Wl);
        gemm_ph<<<256, 512, 0, stream>>>(Xh, Xl, Wh, Wl, H1);    // kh=&1, nb=(>>1)&7, mb=>>4
        snn_scan<<<Bn, 1024, 0, stream>>>(H1, b1, W2, b2, out, 1);
    } else if (ws_size >= WS_R7) {
        _Float16* Xh = (_Float16*)(ws + H1_BYTES);
        _Float16* Xl = (_Float16*)(ws + H1_BYTES + XS_BYTES);
        _Float16* Wh = (_Float16*)(ws + H1_BYTES + 2 * XS_BYTES);
        _Float16* Wl = (_Float16*)(ws + H1_BYTES + 2 * XS_BYTES + WSp_BYTES);

        cvt2<<<256 * 25 + 64 * 25, 256, 0, stream>>>(x, W1, Xh, Xl, Wh, Wl);
        gemm_frag2<<<512, 256, 0, stream>>>(Xh, Xl, Wh, Wl, H1);
        snn_scan<<<Bn, 1024, 0, stream>>>(H1, b1, W2, b2, out, 0);
    } else {
        dim3 grid(Mn / 64, (Hn + 63) / 64);
        gemm_fb<<<grid, 256, 0, stream>>>(x, W1, H1);
        snn_scan<<<Bn, 1024, 0, stream>>>(H1, b1, W2, b2, out, 0);
    }
}

// Round 10
// 344.993 us; speedup vs baseline: 1.0973x; 1.0642x over previous
//
#include <hip/hip_runtime.h>
#include <hip/hip_bf16.h>

// Problem constants (fixed by reference setup_inputs)
constexpr int Bn = 128;   // batch
constexpr int Tn = 32;    // timesteps
constexpr int Dn = 6400;  // input dim (K)
constexpr int Hn = 1000;  // hidden  (N)
constexpr int An = 4;     // actions
constexpr int Mn = Bn * Tn;   // 4096 GEMM rows
constexpr int Npad = 1024;    // W rows padded -> no N-guards in GEMM

constexpr int KS = Dn / 32;   // 200 k-chunks of 32
constexpr int MC = Mn / 16;   // 256 m-chunks of 16 rows
constexpr int NC = Npad / 16; // 64  n-chunks of 16 rows

typedef _Float16 half8 __attribute__((ext_vector_type(8)));
typedef _Float16 half4 __attribute__((ext_vector_type(4)));
typedef float floatx4 __attribute__((ext_vector_type(4)));

// Workspace layouts (bytes)
constexpr size_t H1_BYTES  = (size_t)Mn * Hn * 4;       // 16,384,000
constexpr size_t XS_BYTES  = (size_t)Mn * Dn * 2;       // per split
constexpr size_t WSp_BYTES = (size_t)Npad * Dn * 2;     // per split
constexpr size_t WS_R7     = H1_BYTES + 2 * XS_BYTES + 2 * WSp_BYTES;      // 147,456,000
constexpr size_t WS_SPLITK = 2 * H1_BYTES + 2 * XS_BYTES + 2 * WSp_BYTES;  // 163,840,000

__device__ __forceinline__ void async16(const void* g, void* l) {
    __builtin_amdgcn_global_load_lds(
        (const __attribute__((address_space(1))) void*)g,
        (__attribute__((address_space(3))) void*)l, 16, 0, 0);
}

// ---------------------------------------------------------------------------
// Pre-pass: fp16 hi/lo split into fragment-chunk layout, both sides 1KB
// coalesced via LDS transpose.
// r12 encoding (verified absmax=0): values pre-scaled by 16 (exact exponent
// shift), lo stored UNSCALED: hi = fp16(16*v), lo = fp16(16*v - hi).  All
// three MFMA products (hi*hi, hi*lo, lo*hi) carry coefficient 1 -> single
// accumulator in the GEMM; epilogue multiplies by 1/256.
// ---------------------------------------------------------------------------
__global__ __launch_bounds__(256)
void cvt2(const float* __restrict__ X, const float* __restrict__ W1,
          _Float16* __restrict__ Xh, _Float16* __restrict__ Xl,
          _Float16* __restrict__ Wh, _Float16* __restrict__ Wl)
{
    constexpr int LD2 = 264;
    __shared__ __align__(16) _Float16 hiS[16][LD2];
    __shared__ __align__(16) _Float16 loS[16][LD2];

    const int tid = threadIdx.x;
    const int lane = tid & 63;
    const int w = tid >> 6;
    const int bx = blockIdx.x;

    const float* src;
    _Float16 *dh, *dl;
    int c4, ks0, crow, nrows;
    if (bx < 256 * 25) {                       // X part
        c4 = bx & 255; ks0 = (bx >> 8) * 8;
        src = X; dh = Xh; dl = Xl; crow = MC; nrows = 16;
    } else {                                   // W part (rows >= Hn zeroed)
        const int b2 = bx - 256 * 25;
        c4 = b2 & 63; ks0 = (b2 >> 6) * 8;
        src = W1; dh = Wh; dl = Wl; crow = NC; nrows = Hn - c4 * 16;
    }

#pragma unroll
    for (int j = 0; j < 4; ++j) {
        const int row = w * 4 + j;
        float4 v = make_float4(0.f, 0.f, 0.f, 0.f);
        if (row < nrows)
            v = *(const float4*)(src + (size_t)(c4 * 16 + row) * Dn + ks0 * 32 + lane * 4);
        half4 hi, lo;
        const float vx = v.x * 16.0f, vy = v.y * 16.0f,
                    vz = v.z * 16.0f, vw = v.w * 16.0f;
        hi[0] = (_Float16)vx; lo[0] = (_Float16)(vx - (float)hi[0]);
        hi[1] = (_Float16)vy; lo[1] = (_Float16)(vy - (float)hi[1]);
        hi[2] = (_Float16)vz; lo[2] = (_Float16)(vz - (float)hi[2]);
        hi[3] = (_Float16)vw; lo[3] = (_Float16)(vw - (float)hi[3]);
        *(half4*)&hiS[row][lane * 4] = hi;
        *(half4*)&loS[row][lane * 4] = lo;
    }
    __syncthreads();

    const int lr = lane & 15, lg = lane >> 4;
#pragma unroll
    for (int q = 0; q < 2; ++q) {
        const int ks = w * 2 + q;
        const size_t cbase = ((size_t)(ks0 + ks) * crow + c4) * 512;
        const half8 h = *(const half8*)&hiS[lr][ks * 32 + lg * 8];
        const half8 l = *(const half8*)&loS[lr][ks * 32 + lg * 8];
        *(half8*)(dh + cbase + lane * 8) = h;
        *(half8*)(dl + cbase + lane * 8) = l;
    }
}

// ---------------------------------------------------------------------------
// GEMM primary (r17 "gemm_sk2b"): 128x128 tile, split-K=2, 2 blocks/CU,
// ALL global traffic via LDS-DMA (A *and* B) -- no vector-return vmem.
//
// Post-mortem chain (8 structures):
//  - r8/r9/r11/r12/r14: B direct global->VGPR, MfmaUtil pinned 50-54%.
//    Residual per CU-iter = 3343 - 1863 (MFMA floor) ~ 1480 cyc, ADDITIVE.
//    r14 proved it's not B *latency* (full-iter prefetch: no change).
//  - r13 (both operands via VGPR-return): 44% -- doubling return traffic
//    made it worse.  r15 (3 blocks/CU): 33% -- more blocks made it worse.
//  - r16 (4-phase, thin 12-MFMA phases, B still direct): 40% -- barrier
//    churn without removing the cost.
// Surviving theory: the per-wave B global_loads (64 KB/CU-iter through the
// L1/VGPR-return path) occupy the return port ~1000+ cyc/iter and do NOT
// overlap with MFMA issue (VGPR write-port contention).  The DMA path
// (global_load_lds) is issue-and-forget and bypasses the register file.
// Fix: stage B in LDS via DMA too.  Per buffer (32 KB): rows 0-7 A-hi,
// 8-15 A-lo, 16-23 B-hi, 24-31 B-lo (m/n-chunks, lane-contiguous 1 KB rows
// -> bank-conflict-free).  2-buffer rotation, DMA issued 1 body ahead;
// vmcnt(0) at the barrier is free in steady state (only outstanding vmem =
// DMA(it+1), issued a full body ~2500 cyc earlier).
// Budget/CU-iter: vmem 64 KB all DMA; LDS 192 KB ~ 750 cyc @256B/cyc, well
// under the 1863-cyc MFMA floor (the old "LDS-BW-bound" note applied to the
// 2-accumulator encoding; single-acc has 2.5x headroom).
// Regs: acc 64 AGPR + 16 half8 frag regs + addr ~ 150 -> 2 blocks/CU.
// ---------------------------------------------------------------------------
__global__ __launch_bounds__(256, 2)
void gemm_sk2b(const _Float16* __restrict__ Xh, const _Float16* __restrict__ Xl,
               const _Float16* __restrict__ Wh, const _Float16* __restrict__ Wl,
               float* __restrict__ H1)
{
    __shared__ __align__(16) _Float16 S[2][32][512];   // 64 KB

    const int tid = threadIdx.x;
    const int lane = tid & 63;
    const int w = tid >> 6;                // 0..3
    const int kh = blockIdx.x & 1;
    const int nb = (blockIdx.x >> 1) & 7;
    const int mb = blockIdx.x >> 4;
    const int bm8 = mb * 8;
    const int bn8 = nb * 8;
    const int wm = w & 1;
    const int wn = w >> 1;
    const int ks0 = kh * (KS / 2);
    constexpr int NIT = KS / 2;            // 100 (even)

    // Staging: wave w stages A m-chunks 2w,2w+1 (hi+lo) and B n-chunks
    // 2w,2w+1 (hi+lo) -- 8 async16/wave, 32/block = 32 KB per k-chunk.
    auto issueAB = [&](int ks, int buf) {
        _Float16* base = &S[buf][0][0];
#pragma unroll
        for (int r = 0; r < 2; ++r) {
            const int i = w * 2 + r;       // 0..7
            const size_t ga = ((size_t)(ks * MC + bm8 + i)) * 512 + lane * 8;
            async16(Xh + ga, base + (0 + i) * 512);
            async16(Xl + ga, base + (8 + i) * 512);
            const size_t gb = ((size_t)(ks * NC + bn8 + i)) * 512 + lane * 8;
            async16(Wh + gb, base + (16 + i) * 512);
            async16(Wl + gb, base + (24 + i) * 512);
        }
    };

    floatx4 acc[4][4] = {};                // single accumulator set

    // prologue: DMA(0)->buf0 (8 vmem ops/wave outstanding)
    issueAB(ks0 + 0, 0);

    // Body(IT, BUF): [vmcnt(0); s_barrier] -> issue DMA(IT+1)->BUF^1 ->
    //                16 ds_read from BUF -> 48 MFMA (3 passes x 16).
    // vmcnt(0) at body(IT) waits DMA(IT), issued at top of body(IT-1)
    // (one full body earlier) -- free in steady state, needed at IT=0.
#define SK2B_BODY(IT, BUF)                                                      \
    {                                                                           \
        asm volatile("s_waitcnt vmcnt(0)" ::: "memory");                        \
        __builtin_amdgcn_sched_barrier(0);                                      \
        __builtin_amdgcn_s_barrier();                                           \
        __builtin_amdgcn_sched_barrier(0);                                      \
        if ((IT) + 1 < NIT) issueAB(ks0 + (IT) + 1, (BUF) ^ 1);                 \
        __builtin_amdgcn_sched_barrier(0);                                      \
        half8 ah[4], al[4], bh[4], bl[4];                                       \
        _Pragma("unroll")                                                       \
        for (int mt = 0; mt < 4; ++mt) {                                        \
            ah[mt] = *(const half8*)&S[BUF][0 + wm * 4 + mt][lane * 8];         \
            al[mt] = *(const half8*)&S[BUF][8 + wm * 4 + mt][lane * 8];         \
        }                                                                       \
        _Pragma("unroll")                                                       \
        for (int nt = 0; nt < 4; ++nt) {                                        \
            bh[nt] = *(const half8*)&S[BUF][16 + wn * 4 + nt][lane * 8];        \
            bl[nt] = *(const half8*)&S[BUF][24 + wn * 4 + nt][lane * 8];        \
        }                                                                       \
        _Pragma("unroll")                                                       \
        for (int mt = 0; mt < 4; ++mt)                                          \
            _Pragma("unroll")                                                   \
            for (int nt = 0; nt < 4; ++nt)                                      \
                acc[mt][nt] = __builtin_amdgcn_mfma_f32_16x16x32_f16(ah[mt], bh[nt], acc[mt][nt], 0, 0, 0); \
        _Pragma("unroll")                                                       \
        for (int mt = 0; mt < 4; ++mt)                                          \
            _Pragma("unroll")                                                   \
            for (int nt = 0; nt < 4; ++nt)                                      \
                acc[mt][nt] = __builtin_amdgcn_mfma_f32_16x16x32_f16(ah[mt], bl[nt], acc[mt][nt], 0, 0, 0); \
        _Pragma("unroll")                                                       \
        for (int mt = 0; mt < 4; ++mt)                                          \
            _Pragma("unroll")                                                   \
            for (int nt = 0; nt < 4; ++nt)                                      \
                acc[mt][nt] = __builtin_amdgcn_mfma_f32_16x16x32_f16(al[mt], bh[nt], acc[mt][nt], 0, 0, 0); \
    }

    for (int it = 0; it < NIT; it += 2) {
        SK2B_BODY(it + 0, 0);
        SK2B_BODY(it + 1, 1);
    }
#undef SK2B_BODY

    // epilogue (no bias -- scan adds b1): C/D col=lane&15, row=(lane>>4)*4+r
    // x16 pre-scale on both operands -> result carries 256x; undo here.
    float* H1o = H1 + (size_t)kh * ((size_t)Mn * Hn);
    const int fr = lane & 15;
    const int fq = lane >> 4;
#pragma unroll
    for (int nt = 0; nt < 4; ++nt) {
        const int n = nb * 128 + wn * 64 + nt * 16 + fr;
        if (n >= Hn) continue;
#pragma unroll
        for (int mt = 0; mt < 4; ++mt) {
            const int m = mb * 128 + wm * 64 + mt * 16 + fq * 4;
#pragma unroll
            for (int r = 0; r < 4; ++r)
                H1o[(size_t)(m + r) * Hn + n] = acc[mt][nt][r] * (1.0f / 256.0f);
        }
    }
}

// ---------------------------------------------------------------------------
// GEMM mid-fallback (r7-verified; epilogue updated for x16 encoding):
// ws in [147,164) MB.
// ---------------------------------------------------------------------------
constexpr int AH = 0;
constexpr int AL = 8 * 512;
constexpr int BH = 16 * 512;
constexpr int BL = 20 * 512;
constexpr int BUFSZ = 24 * 512;

__global__ __launch_bounds__(256, 2)
void gemm_frag2(const _Float16* __restrict__ Xh, const _Float16* __restrict__ Xl,
                const _Float16* __restrict__ Wh, const _Float16* __restrict__ Wl,
                float* __restrict__ H1)
{
    __shared__ __align__(16) _Float16 S[2 * BUFSZ];

    const int tid = threadIdx.x;
    const int lane = tid & 63;
    const int w = tid >> 6;
    const int nb = blockIdx.x & 15;
    const int mb = blockIdx.x >> 4;
    const int bm4 = mb * 8;
    const int bn4 = nb * 4;
    const int wm = w & 1;
    const int wn = w >> 1;

    auto issue = [&](int ks, int buf) {
        _Float16* base = &S[buf * BUFSZ];
#pragma unroll
        for (int r = 0; r < 2; ++r) {
            const int i = w * 2 + r;
            const size_t ga = ((size_t)(ks * MC + bm4 + i)) * 512 + lane * 8;
            async16(Xh + ga, base + AH + i * 512);
            async16(Xl + ga, base + AL + i * 512);
        }
        const size_t gb = ((size_t)(ks * NC + bn4 + w)) * 512 + lane * 8;
        async16(Wh + gb, base + BH + w * 512);
        async16(Wl + gb, base + BL + w * 512);
    };

    floatx4 acc0[4][2] = {};
    floatx4 acc1[4][2] = {};

    issue(0, 0);
    for (int it = 0; it < KS; ++it) {
        const int buf = it & 1;
        __syncthreads();
        if (it + 1 < KS) issue(it + 1, buf ^ 1);

        const _Float16* base = &S[buf * BUFSZ];
        half8 ah[4], al[4], bh[2], bl[2];
#pragma unroll
        for (int mt = 0; mt < 4; ++mt) {
            ah[mt] = *(const half8*)(base + AH + (wm * 4 + mt) * 512 + lane * 8);
            al[mt] = *(const half8*)(base + AL + (wm * 4 + mt) * 512 + lane * 8);
        }
#pragma unroll
        for (int nt = 0; nt < 2; ++nt) {
            bh[nt] = *(const half8*)(base + BH + (wn * 2 + nt) * 512 + lane * 8);
            bl[nt] = *(const half8*)(base + BL + (wn * 2 + nt) * 512 + lane * 8);
        }
#pragma unroll
        for (int mt = 0; mt < 4; ++mt)
#pragma unroll
            for (int nt = 0; nt < 2; ++nt) {
                acc0[mt][nt] = __builtin_amdgcn_mfma_f32_16x16x32_f16(ah[mt], bh[nt], acc0[mt][nt], 0, 0, 0);
                acc1[mt][nt] = __builtin_amdgcn_mfma_f32_16x16x32_f16(ah[mt], bl[nt], acc1[mt][nt], 0, 0, 0);
                acc1[mt][nt] = __builtin_amdgcn_mfma_f32_16x16x32_f16(al[mt], bh[nt], acc1[mt][nt], 0, 0, 0);
            }
    }

    const int fr = lane & 15;
    const int fq = lane >> 4;
#pragma unroll
    for (int nt = 0; nt < 2; ++nt) {
        const int n = nb * 64 + wn * 32 + nt * 16 + fr;
        if (n >= Hn) continue;
#pragma unroll
        for (int mt = 0; mt < 4; ++mt) {
            const int m = mb * 128 + wm * 64 + mt * 16 + fq * 4;
#pragma unroll
            for (int r = 0; r < 4; ++r)
                H1[(size_t)(m + r) * Hn + n] =
                    (acc0[mt][nt][r] + acc1[mt][nt][r]) * (1.0f / 256.0f);
        }
    }
}

// ---------------------------------------------------------------------------
// GEMM small-ws fallback (r3-verified; self-contained split, unchanged).
// ---------------------------------------------------------------------------
__global__ __launch_bounds__(256, 4)
void gemm_fb(const float* __restrict__ X, const float* __restrict__ W1,
             float* __restrict__ H1)
{
    constexpr int K = Dn;
    constexpr int LD = 72;
    __shared__ __align__(16) _Float16 As[2][64][LD];
    __shared__ __align__(16) _Float16 Bs[2][64][LD];

    const int tid = threadIdx.x;
    const int bm = blockIdx.x * 64;
    const int bn = blockIdx.y * 64;
    const int lane = tid & 63;
    const int wid = tid >> 6;
    const int wm = (wid & 1) * 32;
    const int wn = (wid >> 1) * 32;
    const int fr = lane & 15;
    const int fq = lane >> 4;

    const int row0 = tid >> 3;
    const int row1 = (tid + 256) >> 3;
    const int k8_0 = (tid & 7) * 8;

    float4 rx[2][2], rw[2][2];
    const float zero4[4] = {0.f, 0.f, 0.f, 0.f};

    auto load_tiles = [&](int k0) {
        rx[0][0] = *(const float4*)(X + (size_t)(bm + row0) * K + k0 + k8_0);
        rx[0][1] = *(const float4*)(X + (size_t)(bm + row0) * K + k0 + k8_0 + 4);
        rx[1][0] = *(const float4*)(X + (size_t)(bm + row1) * K + k0 + k8_0);
        rx[1][1] = *(const float4*)(X + (size_t)(bm + row1) * K + k0 + k8_0 + 4);
        const int n0 = bn + row0, n1 = bn + row1;
        if (n0 < Hn) {
            rw[0][0] = *(const float4*)(W1 + (size_t)n0 * K + k0 + k8_0);
            rw[0][1] = *(const float4*)(W1 + (size_t)n0 * K + k0 + k8_0 + 4);
        } else { rw[0][0] = *(const float4*)zero4; rw[0][1] = *(const float4*)zero4; }
        if (n1 < Hn) {
            rw[1][0] = *(const float4*)(W1 + (size_t)n1 * K + k0 + k8_0);
            rw[1][1] = *(const float4*)(W1 + (size_t)n1 * K + k0 + k8_0 + 4);
        } else { rw[1][0] = *(const float4*)zero4; rw[1][1] = *(const float4*)zero4; }
    };

    load_tiles(0);
    floatx4 acc0[2][2] = {};
    floatx4 acc1[2][2] = {};

    for (int k0 = 0; k0 < K; k0 += 64) {
#pragma unroll
        for (int p = 0; p < 2; ++p) {
            const int row = p ? row1 : row0;
            float v[8];
            *(float4*)&v[0] = rx[p][0]; *(float4*)&v[4] = rx[p][1];
            half8 hi, lo;
#pragma unroll
            for (int j = 0; j < 8; ++j) {
                hi[j] = (_Float16)v[j];
                lo[j] = (_Float16)((v[j] - (float)hi[j]) * 4096.0f);
            }
            *(half8*)&As[0][row][k8_0] = hi;
            *(half8*)&As[1][row][k8_0] = lo;

            *(float4*)&v[0] = rw[p][0]; *(float4*)&v[4] = rw[p][1];
#pragma unroll
            for (int j = 0; j < 8; ++j) {
                hi[j] = (_Float16)v[j];
                lo[j] = (_Float16)((v[j] - (float)hi[j]) * 4096.0f);
            }
            *(half8*)&Bs[0][row][k8_0] = hi;
            *(half8*)&Bs[1][row][k8_0] = lo;
        }
        __syncthreads();
        if (k0 + 64 < K) load_tiles(k0 + 64);

#pragma unroll
        for (int c = 0; c < 2; ++c) {
            half8 ahi[2], alo[2], bhi[2], blo[2];
#pragma unroll
            for (int mt = 0; mt < 2; ++mt) {
                ahi[mt] = *(const half8*)&As[0][wm + mt * 16 + fr][c * 32 + fq * 8];
                alo[mt] = *(const half8*)&As[1][wm + mt * 16 + fr][c * 32 + fq * 8];
            }
#pragma unroll
            for (int nt = 0; nt < 2; ++nt) {
                bhi[nt] = *(const half8*)&Bs[0][wn + nt * 16 + fr][c * 32 + fq * 8];
                blo[nt] = *(const half8*)&Bs[1][wn + nt * 16 + fr][c * 32 + fq * 8];
            }
#pragma unroll
            for (int mt = 0; mt < 2; ++mt)
#pragma unroll
                for (int nt = 0; nt < 2; ++nt) {
                    acc0[mt][nt] = __builtin_amdgcn_mfma_f32_16x16x32_f16(ahi[mt], bhi[nt], acc0[mt][nt], 0, 0, 0);
                    acc1[mt][nt] = __builtin_amdgcn_mfma_f32_16x16x32_f16(ahi[mt], blo[nt], acc1[mt][nt], 0, 0, 0);
                    acc1[mt][nt] = __builtin_amdgcn_mfma_f32_16x16x32_f16(alo[mt], bhi[nt], acc1[mt][nt], 0, 0, 0);
                }
        }
        __syncthreads();
    }

#pragma unroll
    for (int nt = 0; nt < 2; ++nt) {
        const int n = bn + wn + nt * 16 + fr;
        if (n >= Hn) continue;
#pragma unroll
        for (int mt = 0; mt < 2; ++mt) {
            const int m = bm + wm + mt * 16 + fq * 4;
#pragma unroll
            for (int r = 0; r < 4; ++r)
                H1[(size_t)(m + r) * Hn + n] =
                    acc0[mt][nt][r] + acc1[mt][nt][r] * (1.0f / 4096.0f);
        }
    }
}

// ---------------------------------------------------------------------------
// LIF scan (r4-r8 verified) + bias add + sum of `split` extra K-partials.
// ---------------------------------------------------------------------------
__global__ __launch_bounds__(1024)
void snn_scan(const float* __restrict__ H1, const float* __restrict__ b1,
              const float* __restrict__ W2, const float* __restrict__ b2,
              float* __restrict__ out, int split)
{
    const int b = blockIdx.x;
    const int tid = threadIdx.x;
    const int lane = tid & 63;
    const int wid = tid >> 6;
    const bool act = (tid < Hn);
    constexpr size_t MH = (size_t)Mn * Hn;

    __shared__ float w2s[1024][5];
    __shared__ unsigned smask[1024];
    __shared__ float h2s[Tn][An];

#pragma unroll
    for (int a = 0; a < An; ++a)
        w2s[tid][a] = act ? W2[a * Hn + tid] : 0.f;

    const float b1v = act ? b1[tid] : 0.f;

    float cur[Tn];
#pragma unroll
    for (int t = 0; t < Tn; ++t) {
        const size_t idx = ((size_t)b * Tn + t) * Hn + tid;
        float c = act ? H1[idx] : 0.f;
        if (act)
            for (int s = 1; s <= split; ++s) c += H1[idx + (size_t)s * MH];
        cur[t] = c + b1v;
    }

    unsigned mask = 0;
    float mem1 = 0.f;
#pragma unroll
    for (int t = 0; t < Tn; ++t) {
        const float reset = (mem1 > 1.0f) ? 1.0f : 0.0f;
        mem1 = (0.99f * mem1 + cur[t]) * (1.0f - reset);
        if (mem1 > 1.0f) mask |= (1u << t);
    }
    smask[tid] = act ? mask : 0u;
    __syncthreads();

#pragma unroll
    for (int tt = 0; tt < 2; ++tt) {
        const int t = wid * 2 + tt;
        float p[An] = {0.f, 0.f, 0.f, 0.f};
        for (int h = lane; h < 1024; h += 64) {
            const float g = (smask[h] >> t) & 1u ? 1.0f : 0.0f;
#pragma unroll
            for (int a = 0; a < An; ++a) p[a] += g * w2s[h][a];
        }
#pragma unroll
        for (int off = 32; off > 0; off >>= 1)
#pragma unroll
            for (int a = 0; a < An; ++a) p[a] += __shfl_down(p[a], off, 64);
        if (lane == 0) {
#pragma unroll
            for (int a = 0; a < An; ++a) h2s[t][a] = p[a];
        }
    }
    __syncthreads();

    if (tid < An) {
        const float bias = b2[tid];
        float mem2 = 0.f;
#pragma unroll
        for (int t = 0; t < Tn; ++t) {
            const float h2 = h2s[t][tid] + bias;
            const float reset = (mem2 > 1.0f) ? 1.0f : 0.0f;
            mem2 = (0.99f * mem2 + h2) * (1.0f - reset);
            out[((size_t)b * Tn + t) * An + tid] = (mem2 > 1.0f) ? 1.0f : 0.0f;
        }
    }
}

extern "C" void kernel_launch(void* const* d_in, const int* in_sizes, int n_in,
                              void* d_out, int out_size, void* d_ws, size_t ws_size,
                              hipStream_t stream) {
    const float* x  = (const float*)d_in[0];   // [B,T,D]
    const float* W1 = (const float*)d_in[1];   // [H,D]
    const float* b1 = (const float*)d_in[2];   // [H]
    const float* W2 = (const float*)d_in[3];   // [A,H]
    const float* b2 = (const float*)d_in[4];   // [A]
    float* out = (float*)d_out;                // [B,T,A]

    char* ws = (char*)d_ws;
    float* H1 = (float*)ws;

    if (ws_size >= WS_SPLITK) {
        _Float16* Xh = (_Float16*)(ws + 2 * H1_BYTES);
        _Float16* Xl = (_Float16*)(ws + 2 * H1_BYTES + XS_BYTES);
        _Float16* Wh = (_Float16*)(ws + 2 * H1_BYTES + 2 * XS_BYTES);
        _Float16* Wl = (_Float16*)(ws + 2 * H1_BYTES + 2 * XS_BYTES + WSp_BYTES);

        cvt2<<<256 * 25 + 64 * 25, 256, 0, stream>>>(x, W1, Xh, Xl, Wh, Wl);
        gemm_sk2b<<<512, 256, 0, stream>>>(Xh, Xl, Wh, Wl, H1);  // kh=&1, nb=(>>1)&7, mb=>>4
        snn_scan<<<Bn, 1024, 0, stream>>>(H1, b1, W2, b2, out, 1);
    } else if (ws_size >= WS_R7) {
        _Float16* Xh = (_Float16*)(ws + H1_BYTES);
        _Float16* Xl = (_Float16*)(ws + H1_BYTES + XS_BYTES);
        _Float16* Wh = (_Float16*)(ws + H1_BYTES + 2 * XS_BYTES);
        _Float16* Wl = (_Float16*)(ws + H1_BYTES + 2 * XS_BYTES + WSp_BYTES);

        cvt2<<<256 * 25 + 64 * 25, 256, 0, stream>>>(x, W1, Xh, Xl, Wh, Wl);
        gemm_frag2<<<512, 256, 0, stream>>>(Xh, Xl, Wh, Wl, H1);
        snn_scan<<<Bn, 1024, 0, stream>>>(H1, b1, W2, b2, out, 0);
    } else {
        dim3 grid(Mn / 64, (Hn + 63) / 64);
        gemm_fb<<<grid, 256, 0, stream>>>(x, W1, H1);
        snn_scan<<<Bn, 1024, 0, stream>>>(H1, b1, W2, b2, out, 0);
    }
}